// Round 2
// baseline (278.373 us; speedup 1.0000x reference)
//
#include <hip/hip_runtime.h>
#include <math.h>

#define BB 8192
#define KK 6
#define EE 5    // K-1
#define CC 1000
#define NV4 250 // CC/4 float4 per row

// ---------------- Fused kernel: CE + gate per sample -----------------------
// One block (384 threads = 6 waves) per sample b. Wave k computes the
// cross-entropy of row (b,k): each lane holds up to 4 float4 (16 floats) in
// registers -> single HBM pass for max + sum-exp. CE values meet in LDS;
// thread 0 runs the 5-step gate recurrence + first-exit cost select and
// writes one per-sample partial to d_ws.
__global__ __launch_bounds__(384) void fused_kernel(
    const float* __restrict__ yh, const int* __restrict__ ys,
    const float* __restrict__ g, const float* __restrict__ costs,
    float* __restrict__ partial)
{
    const int b    = blockIdx.x;
    const int wave = threadIdx.x >> 6;   // k = 0..5
    const int lane = threadIdx.x & 63;

    // Prefetch gate inputs early (only thread 0 uses them, after the barrier)
    float gv[EE], cv[KK];
    if (threadIdx.x == 0) {
#pragma unroll
        for (int e = 0; e < EE; ++e) gv[e] = g[b * EE + e];
#pragma unroll
        for (int k = 0; k < KK; ++k) cv[k] = costs[k];
    }

    const int row_id = b * KK + wave;
    const size_t row = (size_t)row_id * CC;
    const float4* rp = (const float4*)(yh + row);

    const float NEG = -__builtin_inff();
    float4 r[4];
#pragma unroll
    for (int i = 0; i < 4; ++i) {
        const int idx = lane + 64 * i;
        if (idx < NV4) r[i] = rp[idx];
        else           r[i] = make_float4(NEG, NEG, NEG, NEG);
    }

    // row max
    float mx = NEG;
#pragma unroll
    for (int i = 0; i < 4; ++i)
        mx = fmaxf(mx, fmaxf(fmaxf(r[i].x, r[i].y), fmaxf(r[i].z, r[i].w)));
#pragma unroll
    for (int off = 32; off > 0; off >>= 1)
        mx = fmaxf(mx, __shfl_xor(mx, off));

    // sum exp(x - max); exp(-inf - mx) = 0 handles the 6 pad slots
    float s = 0.f;
#pragma unroll
    for (int i = 0; i < 4; ++i) {
        s += __expf(r[i].x - mx);
        s += __expf(r[i].y - mx);
        s += __expf(r[i].z - mx);
        s += __expf(r[i].w - mx);
    }
#pragma unroll
    for (int off = 32; off > 0; off >>= 1)
        s += __shfl_xor(s, off);

    // target logit (same address across the wave -> one broadcast load)
    const float xy = yh[row + (size_t)ys[row_id]];

    __shared__ float ce_s[KK];
    if (lane == 0) ce_s[wave] = mx + __logf(s) - xy;
    __syncthreads();

    if (threadIdx.x == 0) {
        float p = 1.f, gs = 0.f;
#pragma unroll
        for (int e = 0; e < EE; ++e) {
            gs += p * gv[e] * ce_s[e];
            p *= (1.f - gv[e]);
        }
        gs += p * ce_s[EE];                 // p == p_last here

        // first exit with g > 0.5 (down-count -> pure cndmask chain)
        float cost = cv[EE];
#pragma unroll
        for (int e = EE - 1; e >= 0; --e)
            if (gv[e] > 0.5f) cost = cv[e];

        partial[b] = 0.5f * gs + 0.5f * cost;   // (1-ALPHA)=ALPHA=0.5
    }
}

// ---------------- Deterministic final reduction (1 block) ------------------
__global__ __launch_bounds__(256) void reduce_kernel(
    const float* __restrict__ partial, float* __restrict__ out)
{
    float s = 0.f;
#pragma unroll
    for (int i = threadIdx.x; i < BB; i += 256) s += partial[i];
#pragma unroll
    for (int off = 32; off > 0; off >>= 1) s += __shfl_xor(s, off);

    __shared__ float ps[4];
    if ((threadIdx.x & 63) == 0) ps[threadIdx.x >> 6] = s;
    __syncthreads();
    if (threadIdx.x == 0) out[0] = ps[0] + ps[1] + ps[2] + ps[3];
}

extern "C" void kernel_launch(void* const* d_in, const int* in_sizes, int n_in,
                              void* d_out, int out_size, void* d_ws, size_t ws_size,
                              hipStream_t stream)
{
    const int*   ys    = (const int*)  d_in[0];
    const float* yh    = (const float*)d_in[1];
    const float* g     = (const float*)d_in[2];
    const float* costs = (const float*)d_in[3];
    float* out     = (float*)d_out;
    float* partial = (float*)d_ws;      // BB floats = 32 KiB scratch

    fused_kernel<<<BB, 384, 0, stream>>>(yh, ys, g, costs, partial);
    reduce_kernel<<<1, 256, 0, stream>>>(partial, out);
}